// Round 17
// baseline (216.394 us; speedup 1.0000x reference)
//
#include <hip/hip_runtime.h>
#include <hip/hip_bf16.h>

// Shapes (fixed): B=2, S=2048, D=768, H=12, DK=64.
// Reference quirks (faithful): heads split the flat (S*D) buffer => head slab
// pointer = base + bh*S*DK (slab indexed by head-local position sigma, NOT by
// global s); PV uses PRE-softmax score; attn (softmax) is a second output
// concatenated after out in d_out.
//
// R17: (1) vtrans -> b64-gather + register-transpose (load segment count
// 16x lower); (2) attn pass-B stores nontemporal (402MB write-once stream).
// Attn structure + GEMMs = R16-exact.

#define S_LEN   2048
#define D_MODEL 768
#define NHEAD   12
#define DKH     64
#define BSROWS  4096            // B*S
#define HEADSZ  (S_LEN * DKH)   // 131072 elements per (b,h) head slab
#define WELEMS  (D_MODEL * D_MODEL)   // 589824

typedef __attribute__((ext_vector_type(4))) float f32x4;
typedef __attribute__((ext_vector_type(8))) short s16x8;
typedef __attribute__((ext_vector_type(4))) short s16x4;

// Packed f32x2 -> bf16x2 (RNE), single instruction on gfx950.
static __device__ __forceinline__ unsigned cvtpk(float lo, float hi) {
    unsigned r;
    asm("v_cvt_pk_bf16_f32 %0, %1, %2" : "=v"(r) : "v"(lo), "v"(hi));
    return r;
}

static __device__ __forceinline__ short f2bf(float f) {
    return (short)cvtpk(f, f);      // low 16 bits = bf16(f)
}

static __device__ __forceinline__ s16x8 cvt8(f32x4 a, f32x4 b) {
    union { unsigned u[4]; s16x8 v; } o;
    o.u[0] = cvtpk(a[0], a[1]);
    o.u[1] = cvtpk(a[2], a[3]);
    o.u[2] = cvtpk(b[0], b[1]);
    o.u[3] = cvtpk(b[2], b[3]);
    return o.v;
}

// async global->LDS, 16B/lane; lds dest must be wave-uniform (HW adds lane*16)
static __device__ __forceinline__ void gload16(const void* g, void* l) {
    __builtin_amdgcn_global_load_lds((const __attribute__((address_space(1))) void*)g,
                                     (__attribute__((address_space(3))) void*)l, 16, 0, 0);
}

// Swizzled fragment read from a [rows][64] bf16 tile (128B rows; chunks were
// stored at (c ^ (row&7))). c16 = 16B-chunk index 0..7.
static __device__ __forceinline__ s16x8 ldfrag(const short* tile, int row, int c16) {
    int byte = row * 128 + ((c16 * 16) ^ ((row & 7) << 4));
    return *(const s16x8*)((const char*)tile + byte);
}

// ---------------------------------------------------------------------------
// W f32 -> bf16 prepass (4 matrices of 768x768)
// ---------------------------------------------------------------------------
__global__ __launch_bounds__(256) void prep_w(const float* __restrict__ W0,
                                              const float* __restrict__ W1,
                                              const float* __restrict__ W2,
                                              const float* __restrict__ W3,
                                              short* __restrict__ dst)
{
    const float* src = (blockIdx.y == 0) ? W0 : (blockIdx.y == 1) ? W1
                     : (blockIdx.y == 2) ? W2 : W3;
    short* d = dst + (size_t)blockIdx.y * WELEMS;
    int i = (blockIdx.x * 256 + threadIdx.x) * 8;
    f32x4 a = *(const f32x4*)(src + i);
    f32x4 b = *(const f32x4*)(src + i + 4);
    *(s16x8*)(d + i) = cvt8(a, b);
}

// ---------------------------------------------------------------------------
// QKV GEMM body: 128x96 tile, BK=64, 256 threads = 4 waves (2x2),
// wave = 64 rows x 48 cols (acc 4x3).  A = f32 reg-staged; B = bf16 gload.
// ---------------------------------------------------------------------------
static __device__ __forceinline__ void gemm_qkv_body(const float* __restrict__ Av,
                                                     const short* __restrict__ Wb,
                                                     const float* __restrict__ bias,
                                                     short* __restrict__ Cv,
                                                     int mt, int nt)
{
    __shared__ short As[8192];   // [128][64] swizzled
    __shared__ short Bs[6144];   // [96][64] swizzled
    const int t = threadIdx.x, w = t >> 6, lane = t & 63;
    const int lrow = lane & 15, lgrp = lane >> 4;
    const int wr = w >> 1, wc = w & 1;

    f32x4 acc[4][3];
#pragma unroll
    for (int m = 0; m < 4; ++m)
#pragma unroll
        for (int n = 0; n < 3; ++n) acc[m][n] = {0.f, 0.f, 0.f, 0.f};

    for (int kk = 0; kk < 768; kk += 64) {
        __syncthreads();
#pragma unroll
        for (int j = 0; j < 3; ++j) {              // B tile: 12KB via gload
            int cid = t + j * 256, row = cid >> 3, ch = cid & 7;
            gload16(Wb + (size_t)(nt * 96 + row) * 768 + kk + ((ch ^ (row & 7)) * 8),
                    (char*)Bs + j * 4096 + w * 1024);
        }
#pragma unroll
        for (int j = 0; j < 2; ++j) {              // A tile: f32 -> bf16 regs -> LDS
            int cid = t + j * 256, row = cid >> 2, q4 = cid & 3;
            const float* src = Av + (size_t)(mt * 128 + row) * 768 + kk + q4 * 16;
            f32x4 v0 = *(const f32x4*)(src);
            f32x4 v1 = *(const f32x4*)(src + 4);
            f32x4 v2 = *(const f32x4*)(src + 8);
            f32x4 v3 = *(const f32x4*)(src + 12);
            int c0 = q4 * 2;
            *(s16x8*)((char*)As + row * 128 + (((c0    ) ^ (row & 7)) * 16)) = cvt8(v0, v1);
            *(s16x8*)((char*)As + row * 128 + (((c0 + 1) ^ (row & 7)) * 16)) = cvt8(v2, v3);
        }
        __syncthreads();
#pragma unroll
        for (int kc = 0; kc < 2; ++kc) {
            s16x8 af[4], bfr[3];
#pragma unroll
            for (int m = 0; m < 4; ++m) af[m] = ldfrag(As, wr * 64 + m * 16 + lrow, kc * 4 + lgrp);
#pragma unroll
            for (int n = 0; n < 3; ++n) bfr[n] = ldfrag(Bs, wc * 48 + n * 16 + lrow, kc * 4 + lgrp);
            __builtin_amdgcn_s_setprio(1);
#pragma unroll
            for (int m = 0; m < 4; ++m)
#pragma unroll
                for (int n = 0; n < 3; ++n)
                    acc[m][n] = __builtin_amdgcn_mfma_f32_16x16x32_bf16(af[m], bfr[n], acc[m][n], 0, 0, 0);
            __builtin_amdgcn_s_setprio(0);
        }
    }
#pragma unroll
    for (int n = 0; n < 3; ++n) {
        int col = nt * 96 + wc * 48 + n * 16 + lrow;
        float bvv = bias[col];
#pragma unroll
        for (int m = 0; m < 4; ++m)
#pragma unroll
            for (int r = 0; r < 4; ++r) {
                int row = mt * 128 + wr * 64 + m * 16 + lgrp * 4 + r;
                Cv[(size_t)row * 768 + col] = f2bf(acc[m][n][r] + bvv);
            }
    }
}

// QKV fused: 768 blocks (96 panels x 8 nt), exactly 3 blocks/CU; XCD
// panel-chunked so the 8 nt-blocks of an A-panel run on one XCD.
__global__ __launch_bounds__(256) void gemm_qkv(const float* __restrict__ q,
                                                const float* __restrict__ k,
                                                const float* __restrict__ v,
                                                const short* __restrict__ Wbf,
                                                const float* __restrict__ bq,
                                                const float* __restrict__ bk,
                                                const float* __restrict__ bv,
                                                short* __restrict__ Qw,
                                                short* __restrict__ Kw,
                                                short* __restrict__ Vw)
{
    const int bid = blockIdx.x;
    const int idx = bid >> 3;                      // 0..95
    const int panel = (bid & 7) * 12 + idx / 8;    // 96 panels = 32 mt x 3 z
    const int nt = idx & 7;
    const int z = panel / 32, mt = panel % 32;
    const float* A; const float* bias; short* C;
    if (z == 0)      { A = q; bias = bq; C = Qw; }
    else if (z == 1) { A = k; bias = bk; C = Kw; }
    else             { A = v; bias = bv; C = Vw; }
    gemm_qkv_body(A, Wbf + (size_t)z * WELEMS, bias, C, mt, nt);
}

// ---------------------------------------------------------------------------
// GEMM 64x64 tile, BK=64, 256 threads = 4 waves (2x2), each wave 32x32.
// ---------------------------------------------------------------------------
static __device__ __forceinline__ void gemm_body64(const short* __restrict__ Av,
                                                   const short* __restrict__ Wb,
                                                   const float* __restrict__ bias,
                                                   float* __restrict__ Cv,
                                                   int mt, int nt)
{
    __shared__ short As[4096];   // [64][64] swizzled
    __shared__ short Bs[4096];
    const int t = threadIdx.x, w = t >> 6, lane = t & 63;
    const int lrow = lane & 15, lgrp = lane >> 4;
    const int wr = w >> 1, wc = w & 1;

    f32x4 acc[2][2];
#pragma unroll
    for (int m = 0; m < 2; ++m)
#pragma unroll
        for (int n = 0; n < 2; ++n) acc[m][n] = {0.f, 0.f, 0.f, 0.f};

    for (int kk = 0; kk < 768; kk += 64) {
        __syncthreads();
#pragma unroll
        for (int j = 0; j < 2; ++j) {
            int cid = t + j * 256, row = cid >> 3, ch = cid & 7;
            int cs = (ch ^ (row & 7)) * 8;
            gload16(Av + (size_t)(mt * 64 + row) * 768 + kk + cs,
                    As + w * 512 + j * 2048);
            gload16(Wb + (size_t)(nt * 64 + row) * 768 + kk + cs,
                    Bs + w * 512 + j * 2048);
        }
        __syncthreads();
#pragma unroll
        for (int kc = 0; kc < 2; ++kc) {
            s16x8 af[2], bfr[2];
#pragma unroll
            for (int m = 0; m < 2; ++m) af[m] = ldfrag(As, wr * 32 + m * 16 + lrow, kc * 4 + lgrp);
#pragma unroll
            for (int n = 0; n < 2; ++n) bfr[n] = ldfrag(Bs, wc * 32 + n * 16 + lrow, kc * 4 + lgrp);
            __builtin_amdgcn_s_setprio(1);
#pragma unroll
            for (int m = 0; m < 2; ++m)
#pragma unroll
                for (int n = 0; n < 2; ++n)
                    acc[m][n] = __builtin_amdgcn_mfma_f32_16x16x32_bf16(af[m], bfr[n], acc[m][n], 0, 0, 0);
            __builtin_amdgcn_s_setprio(0);
        }
    }
#pragma unroll
    for (int n = 0; n < 2; ++n) {
        int col = nt * 64 + wc * 32 + n * 16 + lrow;
        float bvv = bias[col];
#pragma unroll
        for (int m = 0; m < 2; ++m)
#pragma unroll
            for (int r = 0; r < 4; ++r) {
                int row = mt * 64 + wr * 32 + m * 16 + lgrp * 4 + r;
                Cv[(size_t)row * 768 + col] = acc[m][n][r] + bvv;
            }
    }
}

// gemm_out: 768 blocks (64 mt x 12 nt), XCD panel-chunked.
__global__ __launch_bounds__(256) void gemm_out(const short* __restrict__ Ob,
                                                const short* __restrict__ Wcb,
                                                const float* __restrict__ bc,
                                                float* __restrict__ out)
{
    const int bid = blockIdx.x;
    const int idx = (bid & 7) * 96 + (bid >> 3);
    const int mt = idx / 12, nt = idx % 12;
    gemm_body64(Ob, Wcb, bc, out, mt, nt);
}

// ---------------------------------------------------------------------------
// V^T per head (R17): Vt[bh][dk][sigma] from Vw head slab [bh][sigma][dk].
// 128 threads; thread owns a 4dk x 8sigma subtile: 8 x b64 loads (wave
// pattern: 8 x 64B contiguous segments), register transpose, 4 x b128
// coalesced stores.  Replaces 16 scalar 2B gathers/thread (64 line-touches
// per load instruction).
// ---------------------------------------------------------------------------
__global__ __launch_bounds__(128) void vtrans(const short* __restrict__ Vw,
                                              short* __restrict__ Vt)
{
    const int sblk = blockIdx.x, bh = blockIdx.y;
    const short* src = Vw + (size_t)bh * HEADSZ + (size_t)sblk * 64 * DKH;
    short* dst = Vt + (size_t)bh * HEADSZ + sblk * 64;
    const int t = threadIdx.x;
    const int dkg = t >> 3, sg = t & 7;      // dkg 0..15 (4 dk each), sg 0..7 (8 sigma each)

    s16x4 v[8];
#pragma unroll
    for (int e = 0; e < 8; ++e)
        v[e] = *(const s16x4*)(src + (size_t)(sg * 8 + e) * DKH + dkg * 4);
#pragma unroll
    for (int d = 0; d < 4; ++d) {
        s16x8 o;
#pragma unroll
        for (int e = 0; e < 8; ++e) o[e] = v[e][d];
        *(s16x8*)(dst + (size_t)(dkg * 4 + d) * S_LEN + sg * 8) = o;
    }
}

// ---------------------------------------------------------------------------
// Fused attention R14-EXACT structure (200.6us validated) + R17 nt stores.
// 256 threads = 4 waves, pass-A k-split quadrants (wave w: qh=w&1 -> 32 q,
// kh=w>>1 -> 32 k), swapped QK^T (mfma(K,Q)) -> b64 strip writes; V staged
// via DMA dbuf.  Pass B: 4-deep K ring, one barrier per 2 k-tiles,
// nontemporal f32x4 attn stores (write-once 402MB stream).
// LDS map (shorts): [0..4095] Q tile -> per-wave [32q][32k] strips (w*1024),
// fvz at 0 | [4096..12287] K dbuf | [12288..20479] V dbuf -> pvx | pass-B
// 4-slot ring spans 4096..20479.
// ---------------------------------------------------------------------------
__global__ __launch_bounds__(256, 4) void attn_fused2(const short* __restrict__ Qb,
                                                      const short* __restrict__ Kb,
                                                      const short* __restrict__ Vtb,
                                                      short* __restrict__ Ob,
                                                      float* __restrict__ attn)
{
    __shared__ short lds[20480];        // 40 KB
    short* Qs = lds;
    const float CE = 0.18033688f;       // log2(e)/8

    const int bid = blockIdx.x;
    const int swz = (bid & 7) * 96 + (bid >> 3);    // XCD-contiguous heads
    const int qb = swz & 31, bh = swz >> 5;
    const int t = threadIdx.x, w = t >> 6, lane = t & 63;
    const int lrow = lane & 15, lgrp = lane >> 4;
    const int qh = w & 1, kh = w >> 1;
    const int b = bh / NHEAD, h = bh % NHEAD;
    const short* Qh = Qb + (size_t)bh * HEADSZ;
    const short* Kh = Kb + (size_t)bh * HEADSZ;
    const short* Vth = Vtb + (size_t)bh * HEADSZ;   // [64 dk][2048 sigma]
    const int q0 = qb * 64;

// 256-thread staging: j=0..1, 16B/lane
#define STAGE_K4(dst, kt) do {                                                  \
    _Pragma("unroll")                                                           \
    for (int j = 0; j < 2; ++j) {                                               \
        int cid = t + j * 256, row = cid >> 3, ch = cid & 7;                    \
        gload16(Kh + (size_t)((kt) * 64 + row) * DKH + ((ch ^ (row & 7)) * 8),  \
                (dst) + w * 512 + j * 2048);                                    \
    } } while (0)

#define STAGE_V4(dst, kt) do {                                                  \
    _Pragma("unroll")                                                           \
    for (int j = 0; j < 2; ++j) {                                               \
        int cid = t + j * 256, row = cid >> 3, ch = cid & 7;                    \
        gload16(Vth + (size_t)row * S_LEN + (kt) * 64 + ((ch ^ (row & 7)) * 8), \
                (dst) + w * 512 + j * 2048);                                    \
    } } while (0)

    // Stage Q (once) + first K/V tile.
#pragma unroll
    for (int j = 0; j < 2; ++j) {
        int cid = t + j * 256, row = cid >> 3, ch = cid & 7;
        gload16(Qh + (size_t)(q0 + row) * DKH + ((ch ^ (row & 7)) * 8),
                Qs + w * 512 + j * 2048);
    }
    STAGE_K4(lds + 4096, 0);
    STAGE_V4(lds + 12288, 0);
    __syncthreads();

    // Pass-A frags (qh rows) + pass-B frags (w*16 rows), loaded before the
    // strip alias frees the Q region.
    s16x8 aqA[2][2], aqB[2];
#pragma unroll
    for (int m = 0; m < 2; ++m)
#pragma unroll
        for (int c = 0; c < 2; ++c)
            aqA[m][c] = ldfrag(Qs, qh * 32 + m * 16 + lrow, c * 4 + lgrp);
#pragma unroll
    for (int c = 0; c < 2; ++c)
        aqB[c] = ldfrag(Qs, w * 16 + lrow, c * 4 + lgrp);
    __syncthreads();     // Q region now free for strips

    f32x4 pv[2][4];
#pragma unroll
    for (int m = 0; m < 2; ++m)
#pragma unroll
        for (int n = 0; n < 4; ++n) pv[m][n] = {0.f, 0.f, 0.f, 0.f};
    float zp[2] = {0.f, 0.f};

    short* SW = lds + w * 1024;   // [32 q][32 k] strip, 64B rows, XOR (q>>2)&3
    int cur = 0;

    // ---- Pass A ----
    for (int kt = 0; kt < 32; ++kt) {
        if (kt) __syncthreads();
        if (kt < 31) {
            STAGE_K4(lds + 4096 + (cur ^ 1) * 4096, kt + 1);
            STAGE_V4(lds + 12288 + (cur ^ 1) * 4096, kt + 1);
        }
        const short* Kc = lds + 4096 + cur * 4096;
        const short* Vc = lds + 12288 + cur * 4096;

        // QK^T quadrant, SWAPPED: s[m][n] row = kpos (lgrp*4+r), col = q (lrow).
        f32x4 s[2][2];
#pragma unroll
        for (int m = 0; m < 2; ++m)
#pragma unroll
            for (int n = 0; n < 2; ++n) s[m][n] = {0.f, 0.f, 0.f, 0.f};
        __builtin_amdgcn_s_setprio(1);
#pragma unroll
        for (int n = 0; n < 2; ++n)
#pragma unroll
            for (int c = 0; c < 2; ++c) {
                s16x8 bk = ldfrag(Kc, kh * 32 + n * 16 + lrow, c * 4 + lgrp);
                s[0][n] = __builtin_amdgcn_mfma_f32_16x16x32_bf16(bk, aqA[0][c], s[0][n], 0, 0, 0);
                s[1][n] = __builtin_amdgcn_mfma_f32_16x16x32_bf16(bk, aqA[1][c], s[1][n], 0, 0, 0);
            }
        __builtin_amdgcn_s_setprio(0);

        // exp-sum (lane covers q = m*16+lrow) + b64 strip write (4 bf16,
        // consecutive k).  Byte (k*2)^X with X = ((q>>2)&3)<<4 -- consistent
        // with the PV read below (8-aligned base, +2r never carries past bit2).
#pragma unroll
        for (int m = 0; m < 2; ++m) {
            int qlocal = m * 16 + lrow;
            int X = ((lrow >> 2) & 3) << 4;
#pragma unroll
            for (int n = 0; n < 2; ++n) {
#pragma unroll
                for (int r = 0; r < 4; ++r)
                    zp[m] += exp2f(s[m][n][r] * CE);
                unsigned lo = cvtpk(s[m][n][0] * 0.125f, s[m][n][1] * 0.125f);
                unsigned hi = cvtpk(s[m][n][2] * 0.125f, s[m][n][3] * 0.125f);
                *(unsigned long long*)((char*)SW + qlocal * 64 +
                                       ((n * 32 + lgrp * 8) ^ X))
                    = ((unsigned long long)hi << 32) | lo;
            }
        }

        // PV: A = strip (contraction 32 = this wave's k-half), B = V half.
        s16x8 asb[2];
#pragma unroll
        for (int m = 0; m < 2; ++m) {
            int row = m * 16 + lrow;
            asb[m] = *(const s16x8*)((char*)SW + row * 64 +
                                     ((lgrp * 16) ^ ((((row >> 2) & 3)) << 4)));
        }
        __builtin_amdgcn_s_setprio(1);
#pragma unroll
        for (int n = 0; n < 4; ++n) {
            s16x8 bv = ldfrag(Vc, n * 16 + lrow, kh * 4 + lgrp);
            pv[0][n] = __builtin_amdgcn_mfma_f32_16x16x32_bf16(asb[0], bv, pv[0][n], 0, 0, 0);
            pv[1][n] = __builtin_amdgcn_mfma_f32_16x16x32_bf16(asb[1], bv, pv[1][n], 0, 0, 0);
        }
        __builtin_amdgcn_s_setprio(0);
        cur ^= 1;
    }
    __syncthreads();     // all waves done with K/V dbuf + strips

    // Z partials (lane holds q = m*16+lrow; sum the 4 lgrp lanes via
    // xor-16/32) -> fvz; PV partials: kh=1 waves park to pvx.
    float* fvz = (float*)lds;
    float* pvx = (float*)(lds + 12288);
#pragma unroll
    for (int m = 0; m < 2; ++m) {
        float z = zp[m];
        z += __shfl_xor(z, 16, 64);
        z += __shfl_xor(z, 32, 64);
        if (lane < 16)
            fvz[kh * 64 + qh * 32 + m * 16 + lrow] = z;
    }
    if (kh == 1) {
        float* dst = pvx + qh * 2048 + lane * 4;
#pragma unroll
        for (int m = 0; m < 2; ++m)
#pragma unroll
            for (int n = 0; n < 4; ++n)
                *(f32x4*)(dst + (m * 4 + n) * 256) = pv[m][n];
    }
    __syncthreads();     // fvz + pvx visible

    // Pass-B prologue: stage ring slots 0,1 (K region -- disjoint from the
    // fvz (Q region) and pvx (V region) reads below).
    STAGE_K4(lds + 4096, 0);
    STAGE_K4(lds + 8192, 1);

    // kh=0 waves: merge PV partials + write Ob (concat layout).
    if (kh == 0) {
        const float* src = pvx + qh * 2048 + lane * 4;
#pragma unroll
        for (int m = 0; m < 2; ++m)
#pragma unroll
            for (int n = 0; n < 4; ++n) {
                pv[m][n] += *(const f32x4*)(src + (m * 4 + n) * 256);
#pragma unroll
                for (int r = 0; r < 4; ++r) {
                    int srow = q0 + qh * 32 + m * 16 + lgrp * 4 + r;
                    Ob[((size_t)b * S_LEN + srow) * D_MODEL + h * DKH + n * 16 + lrow]
                        = f2bf(pv[m][n][r]);
                }
            }
    }

    // invz for this wave's pass-B rows (q = w*16 + lrow); fold into exp2 arg.
    float ztot = fvz[w * 16 + lrow] + fvz[64 + w * 16 + lrow];
    float l2invz = -__log2f(ztot);

    // ---- Pass B: 4-deep K ring, one barrier per 2 k-tiles (R12-exact).
    // Slot 2/3 (12288/16384) overwrite pvx only after the first barrier,
    // by which point all pvx reads are complete.
    float* aw = attn + (size_t)bh * S_LEN * S_LEN;
    for (int kt2 = 0; kt2 < 32; kt2 += 2) {
        __syncthreads();                     // slots kt2, kt2+1 ready
        if (kt2 + 2 < 32) {
            STAGE_K4(lds + 4096 + ((kt2 + 2) & 3) * 4096, kt2 + 2);
            STAGE_K4(lds + 4096 + ((kt2 + 3) & 3) * 4096, kt2 + 3);
        }
#pragma unroll
        for (int u = 0; u < 2; ++u) {
            const int kt = kt2 + u;
            const short* Kc = lds + 4096 + (kt & 3) * 4096;
#pragma unroll
            for (int n = 0; n < 4; ++n) {
                f32x4 s = {0.f, 0.f, 0.f, 0.f};
                __builtin_amdgcn_s_setprio(1);
#pragma unroll
                for (int c = 0; c < 2; ++c) {
                    s16x8 bk = ldfrag(Kc, n * 16 + lrow, c * 4 + lgrp);
                    s = __builtin_amdgcn_mfma_f32_16x16x32_bf16(bk, aqB[c], s, 0, 0, 0);
                }
                __builtin_amdgcn_s_setprio(0);
                f32x4 a0;
#pragma unroll
                for (int r = 0; r < 4; ++r)
                    a0[r] = exp2f(fmaf(s[r], CE, l2invz));
                int kbase = kt * 64 + n * 16 + lgrp * 4;
                __builtin_nontemporal_store(a0,
                    (f32x4*)(aw + (size_t)(q0 + w * 16 + lrow) * S_LEN + kbase));
            }
        }
    }
#undef STAGE_K4
#undef STAGE_V4
}

// ---------------------------------------------------------------------------
extern "C" void kernel_launch(void* const* d_in, const int* in_sizes, int n_in,
                              void* d_out, int out_size, void* d_ws, size_t ws_size,
                              hipStream_t stream)
{
    const float* q  = (const float*)d_in[0];
    const float* k  = (const float*)d_in[1];
    const float* v  = (const float*)d_in[2];
    const float* Wq = (const float*)d_in[3];
    const float* bq = (const float*)d_in[4];
    const float* Wk = (const float*)d_in[5];
    const float* bk = (const float*)d_in[6];
    const float* Wv = (const float*)d_in[7];
    const float* bv = (const float*)d_in[8];
    const float* Wc = (const float*)d_in[9];
    const float* bc = (const float*)d_in[10];

    float* out  = (float*)d_out;
    float* attn = out + (size_t)BSROWS * D_MODEL;

    // ws layout (~29.8 MB, R3-proven aliasing): Wbf[4] | Qw | Kw | Vw(->Ob) | Vt
    short* Wbf  = (short*)d_ws;
    short* Qw   = Wbf + (size_t)4 * WELEMS;
    short* Kw   = Qw + (size_t)BSROWS * D_MODEL;
    short* VwOb = Kw + (size_t)BSROWS * D_MODEL;   // Vw, reused as Ob after vtrans
    short* Vt   = VwOb + (size_t)BSROWS * D_MODEL; // [24][64][2048] bf16

    prep_w<<<dim3(288, 4), dim3(256), 0, stream>>>(Wq, Wk, Wv, Wc, Wbf);

    gemm_qkv<<<dim3(768), dim3(256), 0, stream>>>(q, k, v, Wbf, bq, bk, bv,
                                                  Qw, Kw, VwOb);

    vtrans<<<dim3(32, 24), dim3(128), 0, stream>>>(VwOb, Vt);

    attn_fused2<<<dim3(768), dim3(256), 0, stream>>>(Qw, Kw, Vt, VwOb /*Ob*/, attn);

    gemm_out<<<dim3(768), dim3(256), 0, stream>>>(VwOb /*Ob*/, Wbf + (size_t)3 * WELEMS,
                                                  bc, out);
}

// Round 18
// 193.076 us; speedup vs baseline: 1.1208x; 1.1208x over previous
//
#include <hip/hip_runtime.h>
#include <hip/hip_bf16.h>

// Shapes (fixed): B=2, S=2048, D=768, H=12, DK=64.
// Reference quirks (faithful): heads split the flat (S*D) buffer => head slab
// pointer = base + bh*S*DK (slab indexed by head-local position sigma, NOT by
// global s); PV uses PRE-softmax score; attn (softmax) is a second output
// concatenated after out in d_out.
//
// R18: R16-exact (194.4us validated) + ONLY the R17 vtrans rewrite.
// R17's nontemporal attn stores REVERTED (+22us: nt bypasses the fast
// write-combining path on gfx950 -- plain streaming stores win).

#define S_LEN   2048
#define D_MODEL 768
#define NHEAD   12
#define DKH     64
#define BSROWS  4096            // B*S
#define HEADSZ  (S_LEN * DKH)   // 131072 elements per (b,h) head slab
#define WELEMS  (D_MODEL * D_MODEL)   // 589824

typedef __attribute__((ext_vector_type(4))) float f32x4;
typedef __attribute__((ext_vector_type(8))) short s16x8;
typedef __attribute__((ext_vector_type(4))) short s16x4;

// Packed f32x2 -> bf16x2 (RNE), single instruction on gfx950.
static __device__ __forceinline__ unsigned cvtpk(float lo, float hi) {
    unsigned r;
    asm("v_cvt_pk_bf16_f32 %0, %1, %2" : "=v"(r) : "v"(lo), "v"(hi));
    return r;
}

static __device__ __forceinline__ short f2bf(float f) {
    return (short)cvtpk(f, f);      // low 16 bits = bf16(f)
}

static __device__ __forceinline__ s16x8 cvt8(f32x4 a, f32x4 b) {
    union { unsigned u[4]; s16x8 v; } o;
    o.u[0] = cvtpk(a[0], a[1]);
    o.u[1] = cvtpk(a[2], a[3]);
    o.u[2] = cvtpk(b[0], b[1]);
    o.u[3] = cvtpk(b[2], b[3]);
    return o.v;
}

// async global->LDS, 16B/lane; lds dest must be wave-uniform (HW adds lane*16)
static __device__ __forceinline__ void gload16(const void* g, void* l) {
    __builtin_amdgcn_global_load_lds((const __attribute__((address_space(1))) void*)g,
                                     (__attribute__((address_space(3))) void*)l, 16, 0, 0);
}

// Swizzled fragment read from a [rows][64] bf16 tile (128B rows; chunks were
// stored at (c ^ (row&7))). c16 = 16B-chunk index 0..7.
static __device__ __forceinline__ s16x8 ldfrag(const short* tile, int row, int c16) {
    int byte = row * 128 + ((c16 * 16) ^ ((row & 7) << 4));
    return *(const s16x8*)((const char*)tile + byte);
}

// ---------------------------------------------------------------------------
// W f32 -> bf16 prepass (4 matrices of 768x768)
// ---------------------------------------------------------------------------
__global__ __launch_bounds__(256) void prep_w(const float* __restrict__ W0,
                                              const float* __restrict__ W1,
                                              const float* __restrict__ W2,
                                              const float* __restrict__ W3,
                                              short* __restrict__ dst)
{
    const float* src = (blockIdx.y == 0) ? W0 : (blockIdx.y == 1) ? W1
                     : (blockIdx.y == 2) ? W2 : W3;
    short* d = dst + (size_t)blockIdx.y * WELEMS;
    int i = (blockIdx.x * 256 + threadIdx.x) * 8;
    f32x4 a = *(const f32x4*)(src + i);
    f32x4 b = *(const f32x4*)(src + i + 4);
    *(s16x8*)(d + i) = cvt8(a, b);
}

// ---------------------------------------------------------------------------
// QKV GEMM body: 128x96 tile, BK=64, 256 threads = 4 waves (2x2),
// wave = 64 rows x 48 cols (acc 4x3).  A = f32 reg-staged; B = bf16 gload.
// ---------------------------------------------------------------------------
static __device__ __forceinline__ void gemm_qkv_body(const float* __restrict__ Av,
                                                     const short* __restrict__ Wb,
                                                     const float* __restrict__ bias,
                                                     short* __restrict__ Cv,
                                                     int mt, int nt)
{
    __shared__ short As[8192];   // [128][64] swizzled
    __shared__ short Bs[6144];   // [96][64] swizzled
    const int t = threadIdx.x, w = t >> 6, lane = t & 63;
    const int lrow = lane & 15, lgrp = lane >> 4;
    const int wr = w >> 1, wc = w & 1;

    f32x4 acc[4][3];
#pragma unroll
    for (int m = 0; m < 4; ++m)
#pragma unroll
        for (int n = 0; n < 3; ++n) acc[m][n] = {0.f, 0.f, 0.f, 0.f};

    for (int kk = 0; kk < 768; kk += 64) {
        __syncthreads();
#pragma unroll
        for (int j = 0; j < 3; ++j) {              // B tile: 12KB via gload
            int cid = t + j * 256, row = cid >> 3, ch = cid & 7;
            gload16(Wb + (size_t)(nt * 96 + row) * 768 + kk + ((ch ^ (row & 7)) * 8),
                    (char*)Bs + j * 4096 + w * 1024);
        }
#pragma unroll
        for (int j = 0; j < 2; ++j) {              // A tile: f32 -> bf16 regs -> LDS
            int cid = t + j * 256, row = cid >> 2, q4 = cid & 3;
            const float* src = Av + (size_t)(mt * 128 + row) * 768 + kk + q4 * 16;
            f32x4 v0 = *(const f32x4*)(src);
            f32x4 v1 = *(const f32x4*)(src + 4);
            f32x4 v2 = *(const f32x4*)(src + 8);
            f32x4 v3 = *(const f32x4*)(src + 12);
            int c0 = q4 * 2;
            *(s16x8*)((char*)As + row * 128 + (((c0    ) ^ (row & 7)) * 16)) = cvt8(v0, v1);
            *(s16x8*)((char*)As + row * 128 + (((c0 + 1) ^ (row & 7)) * 16)) = cvt8(v2, v3);
        }
        __syncthreads();
#pragma unroll
        for (int kc = 0; kc < 2; ++kc) {
            s16x8 af[4], bfr[3];
#pragma unroll
            for (int m = 0; m < 4; ++m) af[m] = ldfrag(As, wr * 64 + m * 16 + lrow, kc * 4 + lgrp);
#pragma unroll
            for (int n = 0; n < 3; ++n) bfr[n] = ldfrag(Bs, wc * 48 + n * 16 + lrow, kc * 4 + lgrp);
            __builtin_amdgcn_s_setprio(1);
#pragma unroll
            for (int m = 0; m < 4; ++m)
#pragma unroll
                for (int n = 0; n < 3; ++n)
                    acc[m][n] = __builtin_amdgcn_mfma_f32_16x16x32_bf16(af[m], bfr[n], acc[m][n], 0, 0, 0);
            __builtin_amdgcn_s_setprio(0);
        }
    }
#pragma unroll
    for (int n = 0; n < 3; ++n) {
        int col = nt * 96 + wc * 48 + n * 16 + lrow;
        float bvv = bias[col];
#pragma unroll
        for (int m = 0; m < 4; ++m)
#pragma unroll
            for (int r = 0; r < 4; ++r) {
                int row = mt * 128 + wr * 64 + m * 16 + lgrp * 4 + r;
                Cv[(size_t)row * 768 + col] = f2bf(acc[m][n][r] + bvv);
            }
    }
}

// QKV fused: 768 blocks (96 panels x 8 nt), exactly 3 blocks/CU; XCD
// panel-chunked so the 8 nt-blocks of an A-panel run on one XCD.
__global__ __launch_bounds__(256) void gemm_qkv(const float* __restrict__ q,
                                                const float* __restrict__ k,
                                                const float* __restrict__ v,
                                                const short* __restrict__ Wbf,
                                                const float* __restrict__ bq,
                                                const float* __restrict__ bk,
                                                const float* __restrict__ bv,
                                                short* __restrict__ Qw,
                                                short* __restrict__ Kw,
                                                short* __restrict__ Vw)
{
    const int bid = blockIdx.x;
    const int idx = bid >> 3;                      // 0..95
    const int panel = (bid & 7) * 12 + idx / 8;    // 96 panels = 32 mt x 3 z
    const int nt = idx & 7;
    const int z = panel / 32, mt = panel % 32;
    const float* A; const float* bias; short* C;
    if (z == 0)      { A = q; bias = bq; C = Qw; }
    else if (z == 1) { A = k; bias = bk; C = Kw; }
    else             { A = v; bias = bv; C = Vw; }
    gemm_qkv_body(A, Wbf + (size_t)z * WELEMS, bias, C, mt, nt);
}

// ---------------------------------------------------------------------------
// GEMM 64x64 tile, BK=64, 256 threads = 4 waves (2x2), each wave 32x32.
// ---------------------------------------------------------------------------
static __device__ __forceinline__ void gemm_body64(const short* __restrict__ Av,
                                                   const short* __restrict__ Wb,
                                                   const float* __restrict__ bias,
                                                   float* __restrict__ Cv,
                                                   int mt, int nt)
{
    __shared__ short As[4096];   // [64][64] swizzled
    __shared__ short Bs[4096];
    const int t = threadIdx.x, w = t >> 6, lane = t & 63;
    const int lrow = lane & 15, lgrp = lane >> 4;
    const int wr = w >> 1, wc = w & 1;

    f32x4 acc[2][2];
#pragma unroll
    for (int m = 0; m < 2; ++m)
#pragma unroll
        for (int n = 0; n < 2; ++n) acc[m][n] = {0.f, 0.f, 0.f, 0.f};

    for (int kk = 0; kk < 768; kk += 64) {
        __syncthreads();
#pragma unroll
        for (int j = 0; j < 2; ++j) {
            int cid = t + j * 256, row = cid >> 3, ch = cid & 7;
            int cs = (ch ^ (row & 7)) * 8;
            gload16(Av + (size_t)(mt * 64 + row) * 768 + kk + cs,
                    As + w * 512 + j * 2048);
            gload16(Wb + (size_t)(nt * 64 + row) * 768 + kk + cs,
                    Bs + w * 512 + j * 2048);
        }
        __syncthreads();
#pragma unroll
        for (int kc = 0; kc < 2; ++kc) {
            s16x8 af[2], bfr[2];
#pragma unroll
            for (int m = 0; m < 2; ++m) af[m] = ldfrag(As, wr * 32 + m * 16 + lrow, kc * 4 + lgrp);
#pragma unroll
            for (int n = 0; n < 2; ++n) bfr[n] = ldfrag(Bs, wc * 32 + n * 16 + lrow, kc * 4 + lgrp);
            __builtin_amdgcn_s_setprio(1);
#pragma unroll
            for (int m = 0; m < 2; ++m)
#pragma unroll
                for (int n = 0; n < 2; ++n)
                    acc[m][n] = __builtin_amdgcn_mfma_f32_16x16x32_bf16(af[m], bfr[n], acc[m][n], 0, 0, 0);
            __builtin_amdgcn_s_setprio(0);
        }
    }
#pragma unroll
    for (int n = 0; n < 2; ++n) {
        int col = nt * 64 + wc * 32 + n * 16 + lrow;
        float bvv = bias[col];
#pragma unroll
        for (int m = 0; m < 2; ++m)
#pragma unroll
            for (int r = 0; r < 4; ++r) {
                int row = mt * 64 + wr * 32 + m * 16 + lgrp * 4 + r;
                Cv[(size_t)row * 768 + col] = acc[m][n][r] + bvv;
            }
    }
}

// gemm_out: 768 blocks (64 mt x 12 nt), XCD panel-chunked.
__global__ __launch_bounds__(256) void gemm_out(const short* __restrict__ Ob,
                                                const short* __restrict__ Wcb,
                                                const float* __restrict__ bc,
                                                float* __restrict__ out)
{
    const int bid = blockIdx.x;
    const int idx = (bid & 7) * 96 + (bid >> 3);
    const int mt = idx / 12, nt = idx % 12;
    gemm_body64(Ob, Wcb, bc, out, mt, nt);
}

// ---------------------------------------------------------------------------
// V^T per head (R17 rewrite, kept): Vt[bh][dk][sigma] from Vw head slab
// [bh][sigma][dk].  128 threads; thread owns a 4dk x 8sigma subtile:
// 8 x b64 loads (wave: 8 x 128B contiguous segments), register transpose,
// 4 x b128 stores (wave: 16 x 64B segments).
// ---------------------------------------------------------------------------
__global__ __launch_bounds__(128) void vtrans(const short* __restrict__ Vw,
                                              short* __restrict__ Vt)
{
    const int sblk = blockIdx.x, bh = blockIdx.y;
    const short* src = Vw + (size_t)bh * HEADSZ + (size_t)sblk * 64 * DKH;
    short* dst = Vt + (size_t)bh * HEADSZ + sblk * 64;
    const int t = threadIdx.x;
    const int dkg = t >> 3, sg = t & 7;      // dkg 0..15 (4 dk each), sg 0..7 (8 sigma each)

    s16x4 v[8];
#pragma unroll
    for (int e = 0; e < 8; ++e)
        v[e] = *(const s16x4*)(src + (size_t)(sg * 8 + e) * DKH + dkg * 4);
#pragma unroll
    for (int d = 0; d < 4; ++d) {
        s16x8 o;
#pragma unroll
        for (int e = 0; e < 8; ++e) o[e] = v[e][d];
        *(s16x8*)(dst + (size_t)(dkg * 4 + d) * S_LEN + sg * 8) = o;
    }
}

// ---------------------------------------------------------------------------
// Fused attention R14/R16-EXACT (194.4us validated): 256 threads = 4 waves,
// pass-A k-split quadrants (wave w: qh=w&1 -> 32 q, kh=w>>1 -> 32 k),
// swapped QK^T (mfma(K,Q)) -> b64 strip writes; V staged via DMA dbuf.
// Pass B: 4-deep K ring, one barrier per 2 k-tiles, PLAIN f32x4 stores.
// LDS map (shorts): [0..4095] Q tile -> per-wave [32q][32k] strips (w*1024),
// fvz at 0 | [4096..12287] K dbuf | [12288..20479] V dbuf -> pvx | pass-B
// 4-slot ring spans 4096..20479.
// ---------------------------------------------------------------------------
__global__ __launch_bounds__(256, 4) void attn_fused2(const short* __restrict__ Qb,
                                                      const short* __restrict__ Kb,
                                                      const short* __restrict__ Vtb,
                                                      short* __restrict__ Ob,
                                                      float* __restrict__ attn)
{
    __shared__ short lds[20480];        // 40 KB
    short* Qs = lds;
    const float CE = 0.18033688f;       // log2(e)/8

    const int bid = blockIdx.x;
    const int swz = (bid & 7) * 96 + (bid >> 3);    // XCD-contiguous heads
    const int qb = swz & 31, bh = swz >> 5;
    const int t = threadIdx.x, w = t >> 6, lane = t & 63;
    const int lrow = lane & 15, lgrp = lane >> 4;
    const int qh = w & 1, kh = w >> 1;
    const int b = bh / NHEAD, h = bh % NHEAD;
    const short* Qh = Qb + (size_t)bh * HEADSZ;
    const short* Kh = Kb + (size_t)bh * HEADSZ;
    const short* Vth = Vtb + (size_t)bh * HEADSZ;   // [64 dk][2048 sigma]
    const int q0 = qb * 64;

// 256-thread staging: j=0..1, 16B/lane
#define STAGE_K4(dst, kt) do {                                                  \
    _Pragma("unroll")                                                           \
    for (int j = 0; j < 2; ++j) {                                               \
        int cid = t + j * 256, row = cid >> 3, ch = cid & 7;                    \
        gload16(Kh + (size_t)((kt) * 64 + row) * DKH + ((ch ^ (row & 7)) * 8),  \
                (dst) + w * 512 + j * 2048);                                    \
    } } while (0)

#define STAGE_V4(dst, kt) do {                                                  \
    _Pragma("unroll")                                                           \
    for (int j = 0; j < 2; ++j) {                                               \
        int cid = t + j * 256, row = cid >> 3, ch = cid & 7;                    \
        gload16(Vth + (size_t)row * S_LEN + (kt) * 64 + ((ch ^ (row & 7)) * 8), \
                (dst) + w * 512 + j * 2048);                                    \
    } } while (0)

    // Stage Q (once) + first K/V tile.
#pragma unroll
    for (int j = 0; j < 2; ++j) {
        int cid = t + j * 256, row = cid >> 3, ch = cid & 7;
        gload16(Qh + (size_t)(q0 + row) * DKH + ((ch ^ (row & 7)) * 8),
                Qs + w * 512 + j * 2048);
    }
    STAGE_K4(lds + 4096, 0);
    STAGE_V4(lds + 12288, 0);
    __syncthreads();

    // Pass-A frags (qh rows) + pass-B frags (w*16 rows), loaded before the
    // strip alias frees the Q region.
    s16x8 aqA[2][2], aqB[2];
#pragma unroll
    for (int m = 0; m < 2; ++m)
#pragma unroll
        for (int c = 0; c < 2; ++c)
            aqA[m][c] = ldfrag(Qs, qh * 32 + m * 16 + lrow, c * 4 + lgrp);
#pragma unroll
    for (int c = 0; c < 2; ++c)
        aqB[c] = ldfrag(Qs, w * 16 + lrow, c * 4 + lgrp);
    __syncthreads();     // Q region now free for strips

    f32x4 pv[2][4];
#pragma unroll
    for (int m = 0; m < 2; ++m)
#pragma unroll
        for (int n = 0; n < 4; ++n) pv[m][n] = {0.f, 0.f, 0.f, 0.f};
    float zp[2] = {0.f, 0.f};

    short* SW = lds + w * 1024;   // [32 q][32 k] strip, 64B rows, XOR (q>>2)&3
    int cur = 0;

    // ---- Pass A ----
    for (int kt = 0; kt < 32; ++kt) {
        if (kt) __syncthreads();
        if (kt < 31) {
            STAGE_K4(lds + 4096 + (cur ^ 1) * 4096, kt + 1);
            STAGE_V4(lds + 12288 + (cur ^ 1) * 4096, kt + 1);
        }
        const short* Kc = lds + 4096 + cur * 4096;
        const short* Vc = lds + 12288 + cur * 4096;

        // QK^T quadrant, SWAPPED: s[m][n] row = kpos (lgrp*4+r), col = q (lrow).
        f32x4 s[2][2];
#pragma unroll
        for (int m = 0; m < 2; ++m)
#pragma unroll
            for (int n = 0; n < 2; ++n) s[m][n] = {0.f, 0.f, 0.f, 0.f};
        __builtin_amdgcn_s_setprio(1);
#pragma unroll
        for (int n = 0; n < 2; ++n)
#pragma unroll
            for (int c = 0; c < 2; ++c) {
                s16x8 bk = ldfrag(Kc, kh * 32 + n * 16 + lrow, c * 4 + lgrp);
                s[0][n] = __builtin_amdgcn_mfma_f32_16x16x32_bf16(bk, aqA[0][c], s[0][n], 0, 0, 0);
                s[1][n] = __builtin_amdgcn_mfma_f32_16x16x32_bf16(bk, aqA[1][c], s[1][n], 0, 0, 0);
            }
        __builtin_amdgcn_s_setprio(0);

        // exp-sum (lane covers q = m*16+lrow) + b64 strip write (4 bf16,
        // consecutive k).  Byte (k*2)^X with X = ((q>>2)&3)<<4 -- consistent
        // with the PV read below (8-aligned base, +2r never carries past bit2).
#pragma unroll
        for (int m = 0; m < 2; ++m) {
            int qlocal = m * 16 + lrow;
            int X = ((lrow >> 2) & 3) << 4;
#pragma unroll
            for (int n = 0; n < 2; ++n) {
#pragma unroll
                for (int r = 0; r < 4; ++r)
                    zp[m] += exp2f(s[m][n][r] * CE);
                unsigned lo = cvtpk(s[m][n][0] * 0.125f, s[m][n][1] * 0.125f);
                unsigned hi = cvtpk(s[m][n][2] * 0.125f, s[m][n][3] * 0.125f);
                *(unsigned long long*)((char*)SW + qlocal * 64 +
                                       ((n * 32 + lgrp * 8) ^ X))
                    = ((unsigned long long)hi << 32) | lo;
            }
        }

        // PV: A = strip (contraction 32 = this wave's k-half), B = V half.
        s16x8 asb[2];
#pragma unroll
        for (int m = 0; m < 2; ++m) {
            int row = m * 16 + lrow;
            asb[m] = *(const s16x8*)((char*)SW + row * 64 +
                                     ((lgrp * 16) ^ ((((row >> 2) & 3)) << 4)));
        }
        __builtin_amdgcn_s_setprio(1);
#pragma unroll
        for (int n = 0; n < 4; ++n) {
            s16x8 bv = ldfrag(Vc, n * 16 + lrow, kh * 4 + lgrp);
            pv[0][n] = __builtin_amdgcn_mfma_f32_16x16x32_bf16(asb[0], bv, pv[0][n], 0, 0, 0);
            pv[1][n] = __builtin_amdgcn_mfma_f32_16x16x32_bf16(asb[1], bv, pv[1][n], 0, 0, 0);
        }
        __builtin_amdgcn_s_setprio(0);
        cur ^= 1;
    }
    __syncthreads();     // all waves done with K/V dbuf + strips

    // Z partials (lane holds q = m*16+lrow; sum the 4 lgrp lanes via
    // xor-16/32) -> fvz; PV partials: kh=1 waves park to pvx.
    float* fvz = (float*)lds;
    float* pvx = (float*)(lds + 12288);
#pragma unroll
    for (int m = 0; m < 2; ++m) {
        float z = zp[m];
        z += __shfl_xor(z, 16, 64);
        z += __shfl_xor(z, 32, 64);
        if (lane < 16)
            fvz[kh * 64 + qh * 32 + m * 16 + lrow] = z;
    }
    if (kh == 1) {
        float* dst = pvx + qh * 2048 + lane * 4;
#pragma unroll
        for (int m = 0; m < 2; ++m)
#pragma unroll
            for (int n = 0; n < 4; ++n)
                *(f32x4*)(dst + (m * 4 + n) * 256) = pv[m][n];
    }
    __syncthreads();     // fvz + pvx visible

    // Pass-B prologue: stage ring slots 0,1 (K region -- disjoint from the
    // fvz (Q region) and pvx (V region) reads below).
    STAGE_K4(lds + 4096, 0);
    STAGE_K4(lds + 8192, 1);

    // kh=0 waves: merge PV partials + write Ob (concat layout).
    if (kh == 0) {
        const float* src = pvx + qh * 2048 + lane * 4;
#pragma unroll
        for (int m = 0; m < 2; ++m)
#pragma unroll
            for (int n = 0; n < 4; ++n) {
                pv[m][n] += *(const f32x4*)(src + (m * 4 + n) * 256);
#pragma unroll
                for (int r = 0; r < 4; ++r) {
                    int srow = q0 + qh * 32 + m * 16 + lgrp * 4 + r;
                    Ob[((size_t)b * S_LEN + srow) * D_MODEL + h * DKH + n * 16 + lrow]
                        = f2bf(pv[m][n][r]);
                }
            }
    }

    // invz for this wave's pass-B rows (q = w*16 + lrow); fold into exp2 arg.
    float ztot = fvz[w * 16 + lrow] + fvz[64 + w * 16 + lrow];
    float l2invz = -__log2f(ztot);

    // ---- Pass B: 4-deep K ring, one barrier per 2 k-tiles (R12-exact).
    // Slot 2/3 (12288/16384) overwrite pvx only after the first barrier,
    // by which point all pvx reads are complete.
    float* aw = attn + (size_t)bh * S_LEN * S_LEN;
    for (int kt2 = 0; kt2 < 32; kt2 += 2) {
        __syncthreads();                     // slots kt2, kt2+1 ready
        if (kt2 + 2 < 32) {
            STAGE_K4(lds + 4096 + ((kt2 + 2) & 3) * 4096, kt2 + 2);
            STAGE_K4(lds + 4096 + ((kt2 + 3) & 3) * 4096, kt2 + 3);
        }
#pragma unroll
        for (int u = 0; u < 2; ++u) {
            const int kt = kt2 + u;
            const short* Kc = lds + 4096 + (kt & 3) * 4096;
#pragma unroll
            for (int n = 0; n < 4; ++n) {
                f32x4 s = {0.f, 0.f, 0.f, 0.f};
                __builtin_amdgcn_s_setprio(1);
#pragma unroll
                for (int c = 0; c < 2; ++c) {
                    s16x8 bk = ldfrag(Kc, n * 16 + lrow, c * 4 + lgrp);
                    s = __builtin_amdgcn_mfma_f32_16x16x32_bf16(bk, aqB[c], s, 0, 0, 0);
                }
                __builtin_amdgcn_s_setprio(0);
                f32x4 a0;
#pragma unroll
                for (int r = 0; r < 4; ++r)
                    a0[r] = exp2f(fmaf(s[r], CE, l2invz));
                int kbase = kt * 64 + n * 16 + lgrp * 4;
                *(f32x4*)(aw + (size_t)(q0 + w * 16 + lrow) * S_LEN + kbase) = a0;
            }
        }
    }
#undef STAGE_K4
#undef STAGE_V4
}

// ---------------------------------------------------------------------------
extern "C" void kernel_launch(void* const* d_in, const int* in_sizes, int n_in,
                              void* d_out, int out_size, void* d_ws, size_t ws_size,
                              hipStream_t stream)
{
    const float* q  = (const float*)d_in[0];
    const float* k  = (const float*)d_in[1];
    const float* v  = (const float*)d_in[2];
    const float* Wq = (const float*)d_in[3];
    const float* bq = (const float*)d_in[4];
    const float* Wk = (const float*)d_in[5];
    const float* bk = (const float*)d_in[6];
    const float* Wv = (const float*)d_in[7];
    const float* bv = (const float*)d_in[8];
    const float* Wc = (const float*)d_in[9];
    const float* bc = (const float*)d_in[10];

    float* out  = (float*)d_out;
    float* attn = out + (size_t)BSROWS * D_MODEL;

    // ws layout (~29.8 MB, R3-proven aliasing): Wbf[4] | Qw | Kw | Vw(->Ob) | Vt
    short* Wbf  = (short*)d_ws;
    short* Qw   = Wbf + (size_t)4 * WELEMS;
    short* Kw   = Qw + (size_t)BSROWS * D_MODEL;
    short* VwOb = Kw + (size_t)BSROWS * D_MODEL;   // Vw, reused as Ob after vtrans
    short* Vt   = VwOb + (size_t)BSROWS * D_MODEL; // [24][64][2048] bf16

    prep_w<<<dim3(288, 4), dim3(256), 0, stream>>>(Wq, Wk, Wv, Wc, Wbf);

    gemm_qkv<<<dim3(768), dim3(256), 0, stream>>>(q, k, v, Wbf, bq, bk, bv,
                                                  Qw, Kw, VwOb);

    vtrans<<<dim3(32, 24), dim3(128), 0, stream>>>(VwOb, Vt);

    attn_fused2<<<dim3(768), dim3(256), 0, stream>>>(Qw, Kw, Vt, VwOb /*Ob*/, attn);

    gemm_out<<<dim3(768), dim3(256), 0, stream>>>(VwOb /*Ob*/, Wbf + (size_t)3 * WELEMS,
                                                  bc, out);
}

// Round 19
// 188.116 us; speedup vs baseline: 1.1503x; 1.0264x over previous
//
#include <hip/hip_runtime.h>
#include <hip/hip_bf16.h>

// Shapes (fixed): B=2, S=2048, D=768, H=12, DK=64.
// Reference quirks (faithful): heads split the flat (S*D) buffer => head slab
// pointer = base + bh*S*DK (slab indexed by head-local position sigma, NOT by
// global s); PV uses PRE-softmax score; attn (softmax) is a second output
// concatenated after out in d_out.
//
// R19: micros on R18 (193.1us): (1) exp2f -> __builtin_amdgcn_exp2f (raw
// v_exp_f32, no libm guards); (2) gemm_qkv A-loads issued before B-DMA.

#define S_LEN   2048
#define D_MODEL 768
#define NHEAD   12
#define DKH     64
#define BSROWS  4096            // B*S
#define HEADSZ  (S_LEN * DKH)   // 131072 elements per (b,h) head slab
#define WELEMS  (D_MODEL * D_MODEL)   // 589824

typedef __attribute__((ext_vector_type(4))) float f32x4;
typedef __attribute__((ext_vector_type(8))) short s16x8;
typedef __attribute__((ext_vector_type(4))) short s16x4;

#define EXP2(x) __builtin_amdgcn_exp2f(x)

// Packed f32x2 -> bf16x2 (RNE), single instruction on gfx950.
static __device__ __forceinline__ unsigned cvtpk(float lo, float hi) {
    unsigned r;
    asm("v_cvt_pk_bf16_f32 %0, %1, %2" : "=v"(r) : "v"(lo), "v"(hi));
    return r;
}

static __device__ __forceinline__ short f2bf(float f) {
    return (short)cvtpk(f, f);      // low 16 bits = bf16(f)
}

static __device__ __forceinline__ s16x8 cvt8(f32x4 a, f32x4 b) {
    union { unsigned u[4]; s16x8 v; } o;
    o.u[0] = cvtpk(a[0], a[1]);
    o.u[1] = cvtpk(a[2], a[3]);
    o.u[2] = cvtpk(b[0], b[1]);
    o.u[3] = cvtpk(b[2], b[3]);
    return o.v;
}

// async global->LDS, 16B/lane; lds dest must be wave-uniform (HW adds lane*16)
static __device__ __forceinline__ void gload16(const void* g, void* l) {
    __builtin_amdgcn_global_load_lds((const __attribute__((address_space(1))) void*)g,
                                     (__attribute__((address_space(3))) void*)l, 16, 0, 0);
}

// Swizzled fragment read from a [rows][64] bf16 tile (128B rows; chunks were
// stored at (c ^ (row&7))). c16 = 16B-chunk index 0..7.
static __device__ __forceinline__ s16x8 ldfrag(const short* tile, int row, int c16) {
    int byte = row * 128 + ((c16 * 16) ^ ((row & 7) << 4));
    return *(const s16x8*)((const char*)tile + byte);
}

// ---------------------------------------------------------------------------
// W f32 -> bf16 prepass (4 matrices of 768x768)
// ---------------------------------------------------------------------------
__global__ __launch_bounds__(256) void prep_w(const float* __restrict__ W0,
                                              const float* __restrict__ W1,
                                              const float* __restrict__ W2,
                                              const float* __restrict__ W3,
                                              short* __restrict__ dst)
{
    const float* src = (blockIdx.y == 0) ? W0 : (blockIdx.y == 1) ? W1
                     : (blockIdx.y == 2) ? W2 : W3;
    short* d = dst + (size_t)blockIdx.y * WELEMS;
    int i = (blockIdx.x * 256 + threadIdx.x) * 8;
    f32x4 a = *(const f32x4*)(src + i);
    f32x4 b = *(const f32x4*)(src + i + 4);
    *(s16x8*)(d + i) = cvt8(a, b);
}

// ---------------------------------------------------------------------------
// QKV GEMM body: 128x96 tile, BK=64, 256 threads = 4 waves (2x2),
// wave = 64 rows x 48 cols (acc 4x3).  A = f32 reg-staged (loads issued
// FIRST so their latency overlaps B-DMA issue); B = bf16 gload.
// ---------------------------------------------------------------------------
static __device__ __forceinline__ void gemm_qkv_body(const float* __restrict__ Av,
                                                     const short* __restrict__ Wb,
                                                     const float* __restrict__ bias,
                                                     short* __restrict__ Cv,
                                                     int mt, int nt)
{
    __shared__ short As[8192];   // [128][64] swizzled
    __shared__ short Bs[6144];   // [96][64] swizzled
    const int t = threadIdx.x, w = t >> 6, lane = t & 63;
    const int lrow = lane & 15, lgrp = lane >> 4;
    const int wr = w >> 1, wc = w & 1;

    f32x4 acc[4][3];
#pragma unroll
    for (int m = 0; m < 4; ++m)
#pragma unroll
        for (int n = 0; n < 3; ++n) acc[m][n] = {0.f, 0.f, 0.f, 0.f};

    for (int kk = 0; kk < 768; kk += 64) {
        __syncthreads();
        // A tile f32 loads FIRST (latency overlaps the DMA issue below).
        f32x4 av[2][4];
#pragma unroll
        for (int j = 0; j < 2; ++j) {
            int cid = t + j * 256, row = cid >> 2, q4 = cid & 3;
            const float* src = Av + (size_t)(mt * 128 + row) * 768 + kk + q4 * 16;
            av[j][0] = *(const f32x4*)(src);
            av[j][1] = *(const f32x4*)(src + 4);
            av[j][2] = *(const f32x4*)(src + 8);
            av[j][3] = *(const f32x4*)(src + 12);
        }
#pragma unroll
        for (int j = 0; j < 3; ++j) {              // B tile: 12KB via gload
            int cid = t + j * 256, row = cid >> 3, ch = cid & 7;
            gload16(Wb + (size_t)(nt * 96 + row) * 768 + kk + ((ch ^ (row & 7)) * 8),
                    (char*)Bs + j * 4096 + w * 1024);
        }
#pragma unroll
        for (int j = 0; j < 2; ++j) {              // A: cvt -> LDS
            int cid = t + j * 256, row = cid >> 2, q4 = cid & 3;
            int c0 = q4 * 2;
            *(s16x8*)((char*)As + row * 128 + (((c0    ) ^ (row & 7)) * 16)) = cvt8(av[j][0], av[j][1]);
            *(s16x8*)((char*)As + row * 128 + (((c0 + 1) ^ (row & 7)) * 16)) = cvt8(av[j][2], av[j][3]);
        }
        __syncthreads();
#pragma unroll
        for (int kc = 0; kc < 2; ++kc) {
            s16x8 af[4], bfr[3];
#pragma unroll
            for (int m = 0; m < 4; ++m) af[m] = ldfrag(As, wr * 64 + m * 16 + lrow, kc * 4 + lgrp);
#pragma unroll
            for (int n = 0; n < 3; ++n) bfr[n] = ldfrag(Bs, wc * 48 + n * 16 + lrow, kc * 4 + lgrp);
            __builtin_amdgcn_s_setprio(1);
#pragma unroll
            for (int m = 0; m < 4; ++m)
#pragma unroll
                for (int n = 0; n < 3; ++n)
                    acc[m][n] = __builtin_amdgcn_mfma_f32_16x16x32_bf16(af[m], bfr[n], acc[m][n], 0, 0, 0);
            __builtin_amdgcn_s_setprio(0);
        }
    }
#pragma unroll
    for (int n = 0; n < 3; ++n) {
        int col = nt * 96 + wc * 48 + n * 16 + lrow;
        float bvv = bias[col];
#pragma unroll
        for (int m = 0; m < 4; ++m)
#pragma unroll
            for (int r = 0; r < 4; ++r) {
                int row = mt * 128 + wr * 64 + m * 16 + lgrp * 4 + r;
                Cv[(size_t)row * 768 + col] = f2bf(acc[m][n][r] + bvv);
            }
    }
}

// QKV fused: 768 blocks (96 panels x 8 nt), exactly 3 blocks/CU; XCD
// panel-chunked so the 8 nt-blocks of an A-panel run on one XCD.
__global__ __launch_bounds__(256) void gemm_qkv(const float* __restrict__ q,
                                                const float* __restrict__ k,
                                                const float* __restrict__ v,
                                                const short* __restrict__ Wbf,
                                                const float* __restrict__ bq,
                                                const float* __restrict__ bk,
                                                const float* __restrict__ bv,
                                                short* __restrict__ Qw,
                                                short* __restrict__ Kw,
                                                short* __restrict__ Vw)
{
    const int bid = blockIdx.x;
    const int idx = bid >> 3;                      // 0..95
    const int panel = (bid & 7) * 12 + idx / 8;    // 96 panels = 32 mt x 3 z
    const int nt = idx & 7;
    const int z = panel / 32, mt = panel % 32;
    const float* A; const float* bias; short* C;
    if (z == 0)      { A = q; bias = bq; C = Qw; }
    else if (z == 1) { A = k; bias = bk; C = Kw; }
    else             { A = v; bias = bv; C = Vw; }
    gemm_qkv_body(A, Wbf + (size_t)z * WELEMS, bias, C, mt, nt);
}

// ---------------------------------------------------------------------------
// GEMM 64x64 tile, BK=64, 256 threads = 4 waves (2x2), each wave 32x32.
// ---------------------------------------------------------------------------
static __device__ __forceinline__ void gemm_body64(const short* __restrict__ Av,
                                                   const short* __restrict__ Wb,
                                                   const float* __restrict__ bias,
                                                   float* __restrict__ Cv,
                                                   int mt, int nt)
{
    __shared__ short As[4096];   // [64][64] swizzled
    __shared__ short Bs[4096];
    const int t = threadIdx.x, w = t >> 6, lane = t & 63;
    const int lrow = lane & 15, lgrp = lane >> 4;
    const int wr = w >> 1, wc = w & 1;

    f32x4 acc[2][2];
#pragma unroll
    for (int m = 0; m < 2; ++m)
#pragma unroll
        for (int n = 0; n < 2; ++n) acc[m][n] = {0.f, 0.f, 0.f, 0.f};

    for (int kk = 0; kk < 768; kk += 64) {
        __syncthreads();
#pragma unroll
        for (int j = 0; j < 2; ++j) {
            int cid = t + j * 256, row = cid >> 3, ch = cid & 7;
            int cs = (ch ^ (row & 7)) * 8;
            gload16(Av + (size_t)(mt * 64 + row) * 768 + kk + cs,
                    As + w * 512 + j * 2048);
            gload16(Wb + (size_t)(nt * 64 + row) * 768 + kk + cs,
                    Bs + w * 512 + j * 2048);
        }
        __syncthreads();
#pragma unroll
        for (int kc = 0; kc < 2; ++kc) {
            s16x8 af[2], bfr[2];
#pragma unroll
            for (int m = 0; m < 2; ++m) af[m] = ldfrag(As, wr * 32 + m * 16 + lrow, kc * 4 + lgrp);
#pragma unroll
            for (int n = 0; n < 2; ++n) bfr[n] = ldfrag(Bs, wc * 32 + n * 16 + lrow, kc * 4 + lgrp);
            __builtin_amdgcn_s_setprio(1);
#pragma unroll
            for (int m = 0; m < 2; ++m)
#pragma unroll
                for (int n = 0; n < 2; ++n)
                    acc[m][n] = __builtin_amdgcn_mfma_f32_16x16x32_bf16(af[m], bfr[n], acc[m][n], 0, 0, 0);
            __builtin_amdgcn_s_setprio(0);
        }
    }
#pragma unroll
    for (int n = 0; n < 2; ++n) {
        int col = nt * 64 + wc * 32 + n * 16 + lrow;
        float bvv = bias[col];
#pragma unroll
        for (int m = 0; m < 2; ++m)
#pragma unroll
            for (int r = 0; r < 4; ++r) {
                int row = mt * 64 + wr * 32 + m * 16 + lgrp * 4 + r;
                Cv[(size_t)row * 768 + col] = acc[m][n][r] + bvv;
            }
    }
}

// gemm_out: 768 blocks (64 mt x 12 nt), XCD panel-chunked.
__global__ __launch_bounds__(256) void gemm_out(const short* __restrict__ Ob,
                                                const short* __restrict__ Wcb,
                                                const float* __restrict__ bc,
                                                float* __restrict__ out)
{
    const int bid = blockIdx.x;
    const int idx = (bid & 7) * 96 + (bid >> 3);
    const int mt = idx / 12, nt = idx % 12;
    gemm_body64(Ob, Wcb, bc, out, mt, nt);
}

// ---------------------------------------------------------------------------
// V^T per head: Vt[bh][dk][sigma] from Vw head slab [bh][sigma][dk].
// 128 threads; thread owns a 4dk x 8sigma subtile: 8 x b64 loads, register
// transpose, 4 x b128 stores.
// ---------------------------------------------------------------------------
__global__ __launch_bounds__(128) void vtrans(const short* __restrict__ Vw,
                                              short* __restrict__ Vt)
{
    const int sblk = blockIdx.x, bh = blockIdx.y;
    const short* src = Vw + (size_t)bh * HEADSZ + (size_t)sblk * 64 * DKH;
    short* dst = Vt + (size_t)bh * HEADSZ + sblk * 64;
    const int t = threadIdx.x;
    const int dkg = t >> 3, sg = t & 7;

    s16x4 v[8];
#pragma unroll
    for (int e = 0; e < 8; ++e)
        v[e] = *(const s16x4*)(src + (size_t)(sg * 8 + e) * DKH + dkg * 4);
#pragma unroll
    for (int d = 0; d < 4; ++d) {
        s16x8 o;
#pragma unroll
        for (int e = 0; e < 8; ++e) o[e] = v[e][d];
        *(s16x8*)(dst + (size_t)(dkg * 4 + d) * S_LEN + sg * 8) = o;
    }
}

// ---------------------------------------------------------------------------
// Fused attention (R18 structure, 193.1us validated): 256 threads = 4 waves,
// pass-A k-split quadrants (wave w: qh=w&1 -> 32 q, kh=w>>1 -> 32 k),
// swapped QK^T (mfma(K,Q)) -> b64 strip writes; V staged via DMA dbuf.
// Pass B: 4-deep K ring, one barrier per 2 k-tiles, plain f32x4 stores.
// R19: exp2f -> __builtin_amdgcn_exp2f.
// ---------------------------------------------------------------------------
__global__ __launch_bounds__(256, 4) void attn_fused2(const short* __restrict__ Qb,
                                                      const short* __restrict__ Kb,
                                                      const short* __restrict__ Vtb,
                                                      short* __restrict__ Ob,
                                                      float* __restrict__ attn)
{
    __shared__ short lds[20480];        // 40 KB
    short* Qs = lds;
    const float CE = 0.18033688f;       // log2(e)/8

    const int bid = blockIdx.x;
    const int swz = (bid & 7) * 96 + (bid >> 3);    // XCD-contiguous heads
    const int qb = swz & 31, bh = swz >> 5;
    const int t = threadIdx.x, w = t >> 6, lane = t & 63;
    const int lrow = lane & 15, lgrp = lane >> 4;
    const int qh = w & 1, kh = w >> 1;
    const int b = bh / NHEAD, h = bh % NHEAD;
    const short* Qh = Qb + (size_t)bh * HEADSZ;
    const short* Kh = Kb + (size_t)bh * HEADSZ;
    const short* Vth = Vtb + (size_t)bh * HEADSZ;   // [64 dk][2048 sigma]
    const int q0 = qb * 64;

// 256-thread staging: j=0..1, 16B/lane
#define STAGE_K4(dst, kt) do {                                                  \
    _Pragma("unroll")                                                           \
    for (int j = 0; j < 2; ++j) {                                               \
        int cid = t + j * 256, row = cid >> 3, ch = cid & 7;                    \
        gload16(Kh + (size_t)((kt) * 64 + row) * DKH + ((ch ^ (row & 7)) * 8),  \
                (dst) + w * 512 + j * 2048);                                    \
    } } while (0)

#define STAGE_V4(dst, kt) do {                                                  \
    _Pragma("unroll")                                                           \
    for (int j = 0; j < 2; ++j) {                                               \
        int cid = t + j * 256, row = cid >> 3, ch = cid & 7;                    \
        gload16(Vth + (size_t)row * S_LEN + (kt) * 64 + ((ch ^ (row & 7)) * 8), \
                (dst) + w * 512 + j * 2048);                                    \
    } } while (0)

    // Stage Q (once) + first K/V tile.
#pragma unroll
    for (int j = 0; j < 2; ++j) {
        int cid = t + j * 256, row = cid >> 3, ch = cid & 7;
        gload16(Qh + (size_t)(q0 + row) * DKH + ((ch ^ (row & 7)) * 8),
                Qs + w * 512 + j * 2048);
    }
    STAGE_K4(lds + 4096, 0);
    STAGE_V4(lds + 12288, 0);
    __syncthreads();

    // Pass-A frags (qh rows) + pass-B frags (w*16 rows), loaded before the
    // strip alias frees the Q region.
    s16x8 aqA[2][2], aqB[2];
#pragma unroll
    for (int m = 0; m < 2; ++m)
#pragma unroll
        for (int c = 0; c < 2; ++c)
            aqA[m][c] = ldfrag(Qs, qh * 32 + m * 16 + lrow, c * 4 + lgrp);
#pragma unroll
    for (int c = 0; c < 2; ++c)
        aqB[c] = ldfrag(Qs, w * 16 + lrow, c * 4 + lgrp);
    __syncthreads();     // Q region now free for strips

    f32x4 pv[2][4];
#pragma unroll
    for (int m = 0; m < 2; ++m)
#pragma unroll
        for (int n = 0; n < 4; ++n) pv[m][n] = {0.f, 0.f, 0.f, 0.f};
    float zp[2] = {0.f, 0.f};

    short* SW = lds + w * 1024;   // [32 q][32 k] strip, 64B rows, XOR (q>>2)&3
    int cur = 0;

    // ---- Pass A ----
    for (int kt = 0; kt < 32; ++kt) {
        if (kt) __syncthreads();
        if (kt < 31) {
            STAGE_K4(lds + 4096 + (cur ^ 1) * 4096, kt + 1);
            STAGE_V4(lds + 12288 + (cur ^ 1) * 4096, kt + 1);
        }
        const short* Kc = lds + 4096 + cur * 4096;
        const short* Vc = lds + 12288 + cur * 4096;

        // QK^T quadrant, SWAPPED: s[m][n] row = kpos (lgrp*4+r), col = q (lrow).
        f32x4 s[2][2];
#pragma unroll
        for (int m = 0; m < 2; ++m)
#pragma unroll
            for (int n = 0; n < 2; ++n) s[m][n] = {0.f, 0.f, 0.f, 0.f};
        __builtin_amdgcn_s_setprio(1);
#pragma unroll
        for (int n = 0; n < 2; ++n)
#pragma unroll
            for (int c = 0; c < 2; ++c) {
                s16x8 bk = ldfrag(Kc, kh * 32 + n * 16 + lrow, c * 4 + lgrp);
                s[0][n] = __builtin_amdgcn_mfma_f32_16x16x32_bf16(bk, aqA[0][c], s[0][n], 0, 0, 0);
                s[1][n] = __builtin_amdgcn_mfma_f32_16x16x32_bf16(bk, aqA[1][c], s[1][n], 0, 0, 0);
            }
        __builtin_amdgcn_s_setprio(0);

        // exp-sum (lane covers q = m*16+lrow) + b64 strip write (4 bf16,
        // consecutive k).  Byte (k*2)^X with X = ((q>>2)&3)<<4 -- consistent
        // with the PV read below (8-aligned base, +2r never carries past bit2).
#pragma unroll
        for (int m = 0; m < 2; ++m) {
            int qlocal = m * 16 + lrow;
            int X = ((lrow >> 2) & 3) << 4;
#pragma unroll
            for (int n = 0; n < 2; ++n) {
#pragma unroll
                for (int r = 0; r < 4; ++r)
                    zp[m] += EXP2(s[m][n][r] * CE);
                unsigned lo = cvtpk(s[m][n][0] * 0.125f, s[m][n][1] * 0.125f);
                unsigned hi = cvtpk(s[m][n][2] * 0.125f, s[m][n][3] * 0.125f);
                *(unsigned long long*)((char*)SW + qlocal * 64 +
                                       ((n * 32 + lgrp * 8) ^ X))
                    = ((unsigned long long)hi << 32) | lo;
            }
        }

        // PV: A = strip (contraction 32 = this wave's k-half), B = V half.
        s16x8 asb[2];
#pragma unroll
        for (int m = 0; m < 2; ++m) {
            int row = m * 16 + lrow;
            asb[m] = *(const s16x8*)((char*)SW + row * 64 +
                                     ((lgrp * 16) ^ ((((row >> 2) & 3)) << 4)));
        }
        __builtin_amdgcn_s_setprio(1);
#pragma unroll
        for (int n = 0; n < 4; ++n) {
            s16x8 bv = ldfrag(Vc, n * 16 + lrow, kh * 4 + lgrp);
            pv[0][n] = __builtin_amdgcn_mfma_f32_16x16x32_bf16(asb[0], bv, pv[0][n], 0, 0, 0);
            pv[1][n] = __builtin_amdgcn_mfma_f32_16x16x32_bf16(asb[1], bv, pv[1][n], 0, 0, 0);
        }
        __builtin_amdgcn_s_setprio(0);
        cur ^= 1;
    }
    __syncthreads();     // all waves done with K/V dbuf + strips

    // Z partials (lane holds q = m*16+lrow; sum the 4 lgrp lanes via
    // xor-16/32) -> fvz; PV partials: kh=1 waves park to pvx.
    float* fvz = (float*)lds;
    float* pvx = (float*)(lds + 12288);
#pragma unroll
    for (int m = 0; m < 2; ++m) {
        float z = zp[m];
        z += __shfl_xor(z, 16, 64);
        z += __shfl_xor(z, 32, 64);
        if (lane < 16)
            fvz[kh * 64 + qh * 32 + m * 16 + lrow] = z;
    }
    if (kh == 1) {
        float* dst = pvx + qh * 2048 + lane * 4;
#pragma unroll
        for (int m = 0; m < 2; ++m)
#pragma unroll
            for (int n = 0; n < 4; ++n)
                *(f32x4*)(dst + (m * 4 + n) * 256) = pv[m][n];
    }
    __syncthreads();     // fvz + pvx visible

    // Pass-B prologue: stage ring slots 0,1 (K region -- disjoint from the
    // fvz (Q region) and pvx (V region) reads below).
    STAGE_K4(lds + 4096, 0);
    STAGE_K4(lds + 8192, 1);

    // kh=0 waves: merge PV partials + write Ob (concat layout).
    if (kh == 0) {
        const float* src = pvx + qh * 2048 + lane * 4;
#pragma unroll
        for (int m = 0; m < 2; ++m)
#pragma unroll
            for (int n = 0; n < 4; ++n) {
                pv[m][n] += *(const f32x4*)(src + (m * 4 + n) * 256);
#pragma unroll
                for (int r = 0; r < 4; ++r) {
                    int srow = q0 + qh * 32 + m * 16 + lgrp * 4 + r;
                    Ob[((size_t)b * S_LEN + srow) * D_MODEL + h * DKH + n * 16 + lrow]
                        = f2bf(pv[m][n][r]);
                }
            }
    }

    // invz for this wave's pass-B rows (q = w*16 + lrow); fold into exp2 arg.
    float ztot = fvz[w * 16 + lrow] + fvz[64 + w * 16 + lrow];
    float l2invz = -__log2f(ztot);

    // ---- Pass B: 4-deep K ring, one barrier per 2 k-tiles (R12-exact).
    // Slot 2/3 (12288/16384) overwrite pvx only after the first barrier,
    // by which point all pvx reads are complete.
    float* aw = attn + (size_t)bh * S_LEN * S_LEN;
    for (int kt2 = 0; kt2 < 32; kt2 += 2) {
        __syncthreads();                     // slots kt2, kt2+1 ready
        if (kt2 + 2 < 32) {
            STAGE_K4(lds + 4096 + ((kt2 + 2) & 3) * 4096, kt2 + 2);
            STAGE_K4(lds + 4096 + ((kt2 + 3) & 3) * 4096, kt2 + 3);
        }
#pragma unroll
        for (int u = 0; u < 2; ++u) {
            const int kt = kt2 + u;
            const short* Kc = lds + 4096 + (kt & 3) * 4096;
#pragma unroll
            for (int n = 0; n < 4; ++n) {
                f32x4 s = {0.f, 0.f, 0.f, 0.f};
                __builtin_amdgcn_s_setprio(1);
#pragma unroll
                for (int c = 0; c < 2; ++c) {
                    s16x8 bk = ldfrag(Kc, n * 16 + lrow, c * 4 + lgrp);
                    s = __builtin_amdgcn_mfma_f32_16x16x32_bf16(bk, aqB[c], s, 0, 0, 0);
                }
                __builtin_amdgcn_s_setprio(0);
                f32x4 a0;
#pragma unroll
                for (int r = 0; r < 4; ++r)
                    a0[r] = EXP2(fmaf(s[r], CE, l2invz));
                int kbase = kt * 64 + n * 16 + lgrp * 4;
                *(f32x4*)(aw + (size_t)(q0 + w * 16 + lrow) * S_LEN + kbase) = a0;
            }
        }
    }
#undef STAGE_K4
#undef STAGE_V4
}

// ---------------------------------------------------------------------------
extern "C" void kernel_launch(void* const* d_in, const int* in_sizes, int n_in,
                              void* d_out, int out_size, void* d_ws, size_t ws_size,
                              hipStream_t stream)
{
    const float* q  = (const float*)d_in[0];
    const float* k  = (const float*)d_in[1];
    const float* v  = (const float*)d_in[2];
    const float* Wq = (const float*)d_in[3];
    const float* bq = (const float*)d_in[4];
    const float* Wk = (const float*)d_in[5];
    const float* bk = (const float*)d_in[6];
    const float* Wv = (const float*)d_in[7];
    const float* bv = (const float*)d_in[8];
    const float* Wc = (const float*)d_in[9];
    const float* bc = (const float*)d_in[10];

    float* out  = (float*)d_out;
    float* attn = out + (size_t)BSROWS * D_MODEL;

    // ws layout (~29.8 MB, R3-proven aliasing): Wbf[4] | Qw | Kw | Vw(->Ob) | Vt
    short* Wbf  = (short*)d_ws;
    short* Qw   = Wbf + (size_t)4 * WELEMS;
    short* Kw   = Qw + (size_t)BSROWS * D_MODEL;
    short* VwOb = Kw + (size_t)BSROWS * D_MODEL;   // Vw, reused as Ob after vtrans
    short* Vt   = VwOb + (size_t)BSROWS * D_MODEL; // [24][64][2048] bf16

    prep_w<<<dim3(288, 4), dim3(256), 0, stream>>>(Wq, Wk, Wv, Wc, Wbf);

    gemm_qkv<<<dim3(768), dim3(256), 0, stream>>>(q, k, v, Wbf, bq, bk, bv,
                                                  Qw, Kw, VwOb);

    vtrans<<<dim3(32, 24), dim3(128), 0, stream>>>(VwOb, Vt);

    attn_fused2<<<dim3(768), dim3(256), 0, stream>>>(Qw, Kw, Vt, VwOb /*Ob*/, attn);

    gemm_out<<<dim3(768), dim3(256), 0, stream>>>(VwOb /*Ob*/, Wbf + (size_t)3 * WELEMS,
                                                  bc, out);
}